// Round 3
// baseline (9.687 us; speedup 1.0000x reference)
//
#include <hip/hip_runtime.h>

#define IN_F   512
#define OUT_F  1024
#define NR     16      // distinct weight rows used (ROW_IDX[j] = j % 16)
#define DELTA  0.1f

// 512 blocks x 256 threads = 2048 independent 64-lane wave-tasks (same as R2,
// but 4 waves packed per block -> 4x fewer dispatch packets).
// Wave-task id = (batch row b, 64-wide output chunk).
// Lane l loads x[b, l + 64k] (k=0..7, coalesced); all 8 elements have residue
// l%16, so per-residue stats finalize with shfl_xor(16),(32) — no LDS, no
// barriers. Phase 2 broadcasts via __shfl(v, const r) = readlane.
__global__ __launch_bounds__(256)
void conj_kernel(const float* __restrict__ x,
                 const float* __restrict__ w,
                 float* __restrict__ out) {
    const int wid   = blockIdx.x * 4 + (threadIdx.x >> 6);  // 0..2047 wave-task
    const int b     = wid >> 4;        // 0..127
    const int chunk = wid & 15;        // 0..15  (64 outputs each)
    const int l     = threadIdx.x & 63;
    const int o     = chunk * 64 + l;  // output column

    // Issue weight loads first — independent of x, latency overlaps the
    // x-load + reduce chain. Rows 0..15 only (ROW_IDX[j] = j % 16).
    float wv[NR];
    #pragma unroll
    for (int r = 0; r < NR; ++r)
        wv[r] = w[r * OUT_F + o];      // coalesced 256B per wave

    const float* xrow = x + b * IN_F;
    float sx = 0.0f;   // sum |x| for residue l%16
    float sm = 0.0f;   // sum x*(x>=-1)
    float mx = 0.0f;   // max |x|
    #pragma unroll
    for (int k = 0; k < 8; ++k) {
        const float xv = xrow[l + 64 * k];   // coalesced
        const float ax = fabsf(xv);
        sx += ax;
        sm += (xv >= -1.0f) ? xv : 0.0f;
        mx = fmaxf(mx, ax);
    }
    // Combine lanes {r, r+16, r+32, r+48} -> every lane holds full stats
    // for residue l%16.
    sx += __shfl_xor(sx, 16);
    sm += __shfl_xor(sm, 16);
    mx = fmaxf(mx, __shfl_xor(mx, 16));
    sx += __shfl_xor(sx, 32);
    sm += __shfl_xor(sm, 32);
    mx = fmaxf(mx, __shfl_xor(mx, 32));

    float acc = 0.0f;   // masked matmul
    float sab = 0.0f;   // sum |W*x|
    float mxv = 0.0f;   // max |W*x|
    #pragma unroll
    for (int r = 0; r < NR; ++r) {
        const float sm_r = __shfl(sm, r);   // lane r holds residue r (r < 16)
        const float sx_r = __shfl(sx, r);
        const float mx_r = __shfl(mx, r);
        const float aw = fabsf(wv[r]);
        acc += wv[r] * sm_r;
        sab += aw * sx_r;
        mxv = fmaxf(mxv, aw * mx_r);
    }
    out[b * OUT_F + o] = acc + DELTA * (mxv - sab);
}

extern "C" void kernel_launch(void* const* d_in, const int* in_sizes, int n_in,
                              void* d_out, int out_size, void* d_ws, size_t ws_size,
                              hipStream_t stream) {
    const float* x = (const float*)d_in[0];   // (128, 512)  f32
    const float* w = (const float*)d_in[1];   // (32, 1024)  f32
    float* out = (float*)d_out;               // (128, 1024) f32
    conj_kernel<<<512, 256, 0, stream>>>(x, w, out);
}